// Round 1
// 91.370 us; speedup vs baseline: 1.0228x; 1.0228x over previous
//
#include <hip/hip_runtime.h>
#include <hip/hip_bf16.h>

// DETR Hungarian-matcher cost matrix:
//   C[n, m] = 5*L1(pbox_n, tbox_m) - softmax(logits_n)[label_m] - 2*GIoU(n, m)
// N = bs*nq = 14400 rows, M = 800 targets, NC = 256 classes. Output fp32.
//
// R7: 2 rows per wave (was 4). Rationale from R6 counters: matcher dispatch
// is < 42 us (absent from top-5; the 43-us entries are harness workspace
// fills). Remaining kernel cost is split between per-pair VALU issue
// (~105 cyc / 64 outputs) and the serial per-row dependent logits load.
//  - one s_tb read + one label read + one target xyxy/area derivation now
//    feed TWO output rows  -> ~1.1 cyc/output issue cost (was ~1.64)
//  - both rows' logits/pboxes prefetched before the staging barrier; the
//    two softmax shuffle-reductions interleave for 2x ILP
//  - grid 900 -> 1800 blocks: ~7 blocks/CU demand, better latency hiding
//  - non-temporal stores: 46 MB write-once stream, keep L2 for logits
//
// rcp instead of IEEE div: abs error budget 0.4 (2% of max|C|~20).

constexpr float EPS = 1e-7f;

__device__ __forceinline__ float pair_cost_pp(
    const float4& pb, float ax1, float ay1, float ax2, float ay2, float area1,
    const float4& tb, float bx1, float by1, float bx2, float by2, float area2,
    float prob)
{
    const float l1 = fabsf(pb.x - tb.x) + fabsf(pb.y - tb.y)
                   + fabsf(pb.z - tb.z) + fabsf(pb.w - tb.w);

    const float iw = fmaxf(fminf(ax2, bx2) - fmaxf(ax1, bx1), 0.0f);
    const float ih = fmaxf(fminf(ay2, by2) - fmaxf(ay1, by1), 0.0f);
    const float inter = iw * ih;
    const float uni   = area1 + area2 - inter;
    const float iou   = inter * __builtin_amdgcn_rcpf(uni + EPS);

    const float cw = fmaxf(ax2, bx2) - fminf(ax1, bx1);   // >= 0 by constr.
    const float ch = fmaxf(ay2, by2) - fminf(ay1, by1);
    const float carea = cw * ch;

    const float giou = iou - (carea - uni) * __builtin_amdgcn_rcpf(carea + EPS);
    return 5.0f * l1 - prob - 2.0f * giou;
}

// ---------------- optimized kernel: NC==256, M==800 ----------------
__global__ __launch_bounds__(256) void matcher_opt(
    const float* __restrict__ logits,   // [N, 256]
    const float* __restrict__ pboxes,   // [N, 4]  cxcywh
    const int*   __restrict__ labels,   // [800]
    const float* __restrict__ tboxes,   // [800, 4] cxcywh
    float* __restrict__ out,            // [N, 800]
    int N)
{
    const int wave = threadIdx.x >> 6;
    const int lane = threadIdx.x & 63;

    __shared__ float4 s_tb[800];
    __shared__ int    s_lb[800];
    __shared__ float  s_prob[8][256];   // 2 rows per wave

    const int n0 = (blockIdx.x * 4 + wave) * 2;
    const int n1 = n0 + 1;
    const bool v0 = n0 < N;
    const bool v1 = n1 < N;

    // ---- prefetch both rows' inputs BEFORE the barrier: their HBM latency
    //      hides under the target staging + __syncthreads ----
    float4 lg0 = make_float4(0, 0, 0, 0), lg1 = lg0;
    float4 pb0 = make_float4(0, 0, 0, 0), pb1 = pb0;
    if (v0) {
        lg0 = reinterpret_cast<const float4*>(logits)[(size_t)n0 * 64 + lane];
        pb0 = reinterpret_cast<const float4*>(pboxes)[n0];
    }
    if (v1) {
        lg1 = reinterpret_cast<const float4*>(logits)[(size_t)n1 * 64 + lane];
        pb1 = reinterpret_cast<const float4*>(pboxes)[n1];
    }

    // ---- cooperative coalesced staging of targets (once per block) ----
    for (int i = threadIdx.x; i < 800; i += 256) {
        s_tb[i] = reinterpret_cast<const float4*>(tboxes)[i];
        s_lb[i] = labels[i] & 255;       // mask keeps prob gather in-bounds
    }
    __syncthreads();                     // the only block barrier
    if (!v0) return;
    if (!v1) { lg1 = lg0; pb1 = pb0; }   // duplicate row0; c1==c0 bitwise

    // ---- two softmaxes over 256 classes, interleaved for shuffle ILP ----
    float mx0 = fmaxf(fmaxf(lg0.x, lg0.y), fmaxf(lg0.z, lg0.w));
    float mx1 = fmaxf(fmaxf(lg1.x, lg1.y), fmaxf(lg1.z, lg1.w));
    #pragma unroll
    for (int off = 32; off > 0; off >>= 1) {
        mx0 = fmaxf(mx0, __shfl_xor(mx0, off, 64));
        mx1 = fmaxf(mx1, __shfl_xor(mx1, off, 64));
    }
    const float e00 = __expf(lg0.x - mx0), e01 = __expf(lg0.y - mx0);
    const float e02 = __expf(lg0.z - mx0), e03 = __expf(lg0.w - mx0);
    const float e10 = __expf(lg1.x - mx1), e11 = __expf(lg1.y - mx1);
    const float e12 = __expf(lg1.z - mx1), e13 = __expf(lg1.w - mx1);
    float s0 = (e00 + e01) + (e02 + e03);
    float s1 = (e10 + e11) + (e12 + e13);
    #pragma unroll
    for (int off = 32; off > 0; off >>= 1) {
        s0 += __shfl_xor(s0, off, 64);
        s1 += __shfl_xor(s1, off, 64);
    }
    const float inv0 = __builtin_amdgcn_rcpf(s0);
    const float inv1 = __builtin_amdgcn_rcpf(s1);
    float* sp0 = s_prob[wave * 2 + 0];
    float* sp1 = s_prob[wave * 2 + 1];
    reinterpret_cast<float4*>(sp0)[lane] =
        make_float4(e00 * inv0, e01 * inv0, e02 * inv0, e03 * inv0);
    reinterpret_cast<float4*>(sp1)[lane] =
        make_float4(e10 * inv1, e11 * inv1, e12 * inv1, e13 * inv1);
    // wave-private LDS write->read: DS pipe is in-order per wave and the
    // compiler inserts lgkmcnt waits — no barrier needed.

    // ---- row constants for both rows ----
    const float ax10 = pb0.x - 0.5f * pb0.z, ay10 = pb0.y - 0.5f * pb0.w;
    const float ax20 = pb0.x + 0.5f * pb0.z, ay20 = pb0.y + 0.5f * pb0.w;
    const float area10 = pb0.z * pb0.w;
    const float ax11 = pb1.x - 0.5f * pb1.z, ay11 = pb1.y - 0.5f * pb1.w;
    const float ax21 = pb1.x + 0.5f * pb1.z, ay21 = pb1.y + 0.5f * pb1.w;
    const float area11 = pb1.z * pb1.w;

    float* orow0 = out + (size_t)n0 * 800;
    float* orow1 = v1 ? out + (size_t)n1 * 800 : orow0;  // harmless dup write

    // ---- 768 targets: 12 full-wave iterations; one s_tb read + one target
    //      xyxy/area derivation feeds BOTH rows ----
    #pragma unroll 2
    for (int m = lane; m < 768; m += 64) {
        const float4 tb = s_tb[m];
        const int   lbl = s_lb[m];
        const float p0  = sp0[lbl];
        const float p1  = sp1[lbl];
        const float bx1 = tb.x - 0.5f * tb.z, by1 = tb.y - 0.5f * tb.w;
        const float bx2 = tb.x + 0.5f * tb.z, by2 = tb.y + 0.5f * tb.w;
        const float area2 = tb.z * tb.w;
        const float c0 = pair_cost_pp(pb0, ax10, ay10, ax20, ay20, area10,
                                      tb, bx1, by1, bx2, by2, area2, p0);
        const float c1 = pair_cost_pp(pb1, ax11, ay11, ax21, ay21, area11,
                                      tb, bx1, by1, bx2, by2, area2, p1);
        __builtin_nontemporal_store(c0, orow0 + m);
        __builtin_nontemporal_store(c1, orow1 + m);
    }
    // ---- last 32 targets: half-wave tail ----
    if (lane < 32) {
        const int m = 768 + lane;
        const float4 tb = s_tb[m];
        const int   lbl = s_lb[m];
        const float bx1 = tb.x - 0.5f * tb.z, by1 = tb.y - 0.5f * tb.w;
        const float bx2 = tb.x + 0.5f * tb.z, by2 = tb.y + 0.5f * tb.w;
        const float area2 = tb.z * tb.w;
        const float c0 = pair_cost_pp(pb0, ax10, ay10, ax20, ay20, area10,
                                      tb, bx1, by1, bx2, by2, area2, sp0[lbl]);
        const float c1 = pair_cost_pp(pb1, ax11, ay11, ax21, ay21, area11,
                                      tb, bx1, by1, bx2, by2, area2, sp1[lbl]);
        __builtin_nontemporal_store(c0, orow0 + m);
        __builtin_nontemporal_store(c1, orow1 + m);
    }
}

// ---------------- generic fallback (any NC multiple-of-4 >= 4, any M) ------
__global__ __launch_bounds__(256) void matcher_generic(
    const float* __restrict__ logits, const float* __restrict__ pboxes,
    const int* __restrict__ labels, const float* __restrict__ tboxes,
    float* __restrict__ out, int N, int M, int NC, int lbl_mask)
{
    const int wave = threadIdx.x >> 6;
    const int lane = threadIdx.x & 63;
    const int n    = blockIdx.x * 4 + wave;

    extern __shared__ float s_dyn[];           // [4][NC]
    float* sp = s_dyn + wave * NC;

    if (n < N) {
        float mx = -3.4e38f;
        for (int c = lane; c < NC; c += 64) mx = fmaxf(mx, logits[(size_t)n * NC + c]);
        #pragma unroll
        for (int off = 32; off > 0; off >>= 1) mx = fmaxf(mx, __shfl_xor(mx, off, 64));
        float s = 0.f;
        for (int c = lane; c < NC; c += 64) {
            const float e = __expf(logits[(size_t)n * NC + c] - mx);
            sp[c] = e; s += e;
        }
        #pragma unroll
        for (int off = 32; off > 0; off >>= 1) s += __shfl_xor(s, off, 64);
        const float inv = __builtin_amdgcn_rcpf(s);
        for (int c = lane; c < NC; c += 64) sp[c] *= inv;
    }
    __syncthreads();
    if (n >= N) return;

    const float4 pb = reinterpret_cast<const float4*>(pboxes)[n];
    const float ax1 = pb.x - 0.5f * pb.z, ay1 = pb.y - 0.5f * pb.w;
    const float ax2 = pb.x + 0.5f * pb.z, ay2 = pb.y + 0.5f * pb.w;
    const float area1 = pb.z * pb.w;
    float* orow = out + (size_t)n * M;

    for (int m = lane; m < M; m += 64) {
        const float4 tb = reinterpret_cast<const float4*>(tboxes)[m];
        const float bx1 = tb.x - 0.5f * tb.z, by1 = tb.y - 0.5f * tb.w;
        const float bx2 = tb.x + 0.5f * tb.z, by2 = tb.y + 0.5f * tb.w;
        const float area2 = tb.z * tb.w;
        orow[m] = pair_cost_pp(pb, ax1, ay1, ax2, ay2, area1,
                               tb, bx1, by1, bx2, by2, area2,
                               sp[labels[m] & lbl_mask]);
    }
}

extern "C" void kernel_launch(void* const* d_in, const int* in_sizes, int n_in,
                              void* d_out, int out_size, void* d_ws, size_t ws_size,
                              hipStream_t stream) {
    const float* logits = (const float*)d_in[0];   // [N, NC] fp32
    const float* pboxes = (const float*)d_in[1];   // [N, 4]  fp32
    const int*   labels = (const int*)d_in[2];     // [M]     int32
    const float* tboxes = (const float*)d_in[3];   // [M, 4]  fp32

    const int N  = in_sizes[1] / 4;       // pred_boxes: 14400
    const int M  = in_sizes[2];           // 800
    const int NC = in_sizes[0] / N;       // 256

    if (NC == 256 && M == 800) {
        const int waves = (N + 1) / 2;    // 2 rows per wave
        const int grid  = (waves + 3) / 4;
        matcher_opt<<<grid, 256, 0, stream>>>(
            logits, pboxes, labels, tboxes, (float*)d_out, N);
    } else {
        int lbl_mask = 1; while (lbl_mask < NC) lbl_mask <<= 1;  // pow2 >= NC
        --lbl_mask;
        const int grid = (N + 3) / 4;
        matcher_generic<<<grid, 256, 4 * NC * sizeof(float), stream>>>(
            logits, pboxes, labels, tboxes, (float*)d_out, N, M, NC, lbl_mask);
    }
}